// Round 7
// baseline (298.716 us; speedup 1.0000x reference)
//
#include <hip/hip_runtime.h>
#include <hip/hip_bf16.h>

#define T_TOK 2048
#define HID 1024
#define FFNDIM 2048
#define NEXP 8
#define RPADDED 4224
#define YPSTR (RPADDED * HID)

typedef __attribute__((ext_vector_type(8))) short short8;
typedef __attribute__((ext_vector_type(4))) float f32x4;

__device__ inline unsigned short f2bf(float f) {
  union { float f; unsigned int u; } v; v.f = f;
  unsigned int u = v.u;
  unsigned int r = (u + 0x7fffu + ((u >> 16) & 1u)) >> 16;
  return (unsigned short)r;
}

__device__ inline short8 pack8(float4 a, float4 b) {
  union { __hip_bfloat162 h2[4]; short8 s; } u;
  u.h2[0] = __float22bfloat162_rn(float2{a.x, a.y});
  u.h2[1] = __float22bfloat162_rn(float2{a.z, a.w});
  u.h2[2] = __float22bfloat162_rn(float2{b.x, b.y});
  u.h2[3] = __float22bfloat162_rn(float2{b.z, b.w});
  return u.s;
}

__device__ inline void gload_lds16(const void* g, void* l) {
  __builtin_amdgcn_global_load_lds((const __attribute__((address_space(1))) void*)g,
                                   (__attribute__((address_space(3))) void*)l, 16, 0, 0);
}

// ---------------- router ----------------
__global__ __launch_bounds__(256) void router_kernel(
    const float* __restrict__ x, const float* __restrict__ gw,
    int* __restrict__ counts, int* __restrict__ top_i, float* __restrict__ top_w) {
  int lane = threadIdx.x & 63;
  int t = blockIdx.x * 4 + (threadIdx.x >> 6);
  if (t >= T_TOK) return;
  float xv[16];
#pragma unroll
  for (int i = 0; i < 16; ++i) xv[i] = x[(size_t)t * HID + i * 64 + lane];
  float logit[NEXP];
#pragma unroll
  for (int e = 0; e < NEXP; ++e) {
    float s = 0.f;
#pragma unroll
    for (int i = 0; i < 16; ++i) s += xv[i] * gw[e * HID + i * 64 + lane];
#pragma unroll
    for (int off = 32; off > 0; off >>= 1) s += __shfl_xor(s, off);
    logit[e] = s;
  }
  if (lane == 0) {
    float mx = logit[0];
#pragma unroll
    for (int e = 1; e < NEXP; ++e) mx = fmaxf(mx, logit[e]);
    float p[NEXP]; float sum = 0.f;
#pragma unroll
    for (int e = 0; e < NEXP; ++e) { p[e] = expf(logit[e] - mx); sum += p[e]; }
#pragma unroll
    for (int e = 0; e < NEXP; ++e) p[e] /= sum;
    int i0 = 0;
#pragma unroll
    for (int e = 1; e < NEXP; ++e) if (p[e] > p[i0]) i0 = e;
    int i1 = (i0 == 0) ? 1 : 0;
#pragma unroll
    for (int e = 0; e < NEXP; ++e) if (e != i0 && p[e] > p[i1]) i1 = e;
    float w0 = p[i0], w1v = p[i1];
    float s2 = w0 + w1v;
    w0 /= s2; w1v /= s2;
    top_i[t * 2 + 0] = i0; top_i[t * 2 + 1] = i1;
    top_w[t * 2 + 0] = w0; top_w[t * 2 + 1] = w1v;
    atomicAdd(&counts[i0], 1);
    atomicAdd(&counts[i1], 1);
  }
}

__global__ void offsets_kernel(const int* __restrict__ counts, int* __restrict__ offsets) {
  if (threadIdx.x == 0 && blockIdx.x == 0) {
    int s = 0;
    for (int e = 0; e < NEXP; ++e) { offsets[e] = s; s += counts[e]; }
    offsets[NEXP] = s;
  }
}

__global__ __launch_bounds__(256) void scatter_kernel(
    const int* __restrict__ top_i, const float* __restrict__ top_w,
    const int* __restrict__ offsets, int* __restrict__ cursor,
    int* __restrict__ row_tok, int* __restrict__ tok_rows) {
  int t = blockIdx.x * 256 + threadIdx.x;
  if (t >= T_TOK) return;
#pragma unroll
  for (int k = 0; k < 2; ++k) {
    int e = top_i[t * 2 + k];
    int p = atomicAdd(&cursor[e], 1);
    int idx = offsets[e] + p;
    row_tok[idx] = t;
    tok_rows[t * 2 + k] = idx;
  }
}

__global__ __launch_bounds__(256) void gather_kernel(
    const float* __restrict__ x, const int* __restrict__ row_tok,
    unsigned short* __restrict__ Xg) {
  int r = blockIdx.x;
  int t = row_tok[r];
  int c = threadIdx.x * 4;
  float4 v = *reinterpret_cast<const float4*>(x + (size_t)t * HID + c);
  ushort4 o;
  o.x = f2bf(v.x); o.y = f2bf(v.y); o.z = f2bf(v.z); o.w = f2bf(v.w);
  *reinterpret_cast<ushort4*>(Xg + (size_t)r * HID + c) = o;
}

// ======== GEMM1: 128 tokens x 64 ffn-cols x {w1,w3}; 4 waves(2x2); BK=64; NT=16 ========
// B tile 128 rows x 64 K: row r: wn_=r>>6, s=r&63; s<32 -> w1 col ntb+wn_*32+s,
//                                          s>=32 -> w3 col ntb+wn_*32+(s-32).
// Wave (wm,wn): tokens wm*64+mf*16.., B-rows wn*64+nf*16+fr (nf 0,1=w1; 2,3=w3).
__global__ __launch_bounds__(256) void gemm1_v7(
    const unsigned short* __restrict__ Xg,
    const float* __restrict__ w1, const float* __restrict__ w3,
    const int* __restrict__ counts, const int* __restrict__ offsets,
    unsigned short* __restrict__ hbuf) {
  int e = blockIdx.z;
  int cnt = counts[e];
  int nt = blockIdx.x, mt = blockIdx.y;
  if (cnt == 0 || mt * 128 >= cnt) return;
  int off = offsets[e];
  int ntb = nt * 64;

  __shared__ alignas(16) unsigned short sA[2][128 * 64];
  __shared__ alignas(16) unsigned short sB[2][128 * 64];

  int tid = threadIdx.x;
  int lane = tid & 63, wid = tid >> 6;
  int wm = wid >> 1, wn = wid & 1;
  int fr = lane & 15, fq = lane >> 4;

  // ---- A staging: 4 DMA lines; line j covers rows j*32 + wid*8 + (lane>>3) ----
  int g_lin = (((lane & 7) ^ (lane >> 3)) << 3);   // pre-swizzled granule (elems)
  size_t asrc[4];
#pragma unroll
  for (int j = 0; j < 4; ++j) {
    int rg = mt * 128 + j * 32 + wid * 8 + (lane >> 3);
    if (rg > cnt - 1) rg = cnt - 1;
    asrc[j] = (size_t)(off + rg) * HID + g_lin;
  }
#define ASTAGE(P, K0)                                                        \
  do {                                                                       \
    _Pragma("unroll")                                                        \
    for (int j = 0; j < 4; ++j)                                              \
      gload_lds16(Xg + asrc[j] + (K0), &sA[P][(j * 32 + wid * 8) * 64]);     \
  } while (0)

  // ---- B staging: reg-staged fp32; thread: row rb=tid>>1, granules gset..gset+3 ----
  int rb = tid >> 1;
  int gset = (tid & 1) * 4;
  int wn_ = rb >> 6, s_ = rb & 63;
  const float* bmat = (s_ < 32) ? w1 : w3;
  const float* bsrc = bmat + ((size_t)e * FFNDIM + (ntb + wn_ * 32 + (s_ & 31))) * HID;
  int bws[4];
#pragma unroll
  for (int gi = 0; gi < 4; ++gi)
    bws[gi] = rb * 64 + (((gset + gi) ^ (rb & 7)) << 3);

  float4 pA[8], pB[8];
#define BLOADA(K0)                                                           \
  do {                                                                       \
    _Pragma("unroll")                                                        \
    for (int gi = 0; gi < 4; ++gi) {                                         \
      pA[2 * gi]     = *(const float4*)(bsrc + (K0) + (gset + gi) * 8);      \
      pA[2 * gi + 1] = *(const float4*)(bsrc + (K0) + (gset + gi) * 8 + 4);  \
    }                                                                        \
  } while (0)
#define BLOADB(K0)                                                           \
  do {                                                                       \
    _Pragma("unroll")                                                        \
    for (int gi = 0; gi < 4; ++gi) {                                         \
      pB[2 * gi]     = *(const float4*)(bsrc + (K0) + (gset + gi) * 8);      \
      pB[2 * gi + 1] = *(const float4*)(bsrc + (K0) + (gset + gi) * 8 + 4);  \
    }                                                                        \
  } while (0)
#define BWRITEA(P)                                                           \
  do {                                                                       \
    _Pragma("unroll")                                                        \
    for (int gi = 0; gi < 4; ++gi)                                           \
      *reinterpret_cast<short8*>(&sB[P][bws[gi]]) = pack8(pA[2 * gi], pA[2 * gi + 1]); \
  } while (0)
#define BWRITEB(P)                                                           \
  do {                                                                       \
    _Pragma("unroll")                                                        \
    for (int gi = 0; gi < 4; ++gi)                                           \
      *reinterpret_cast<short8*>(&sB[P][bws[gi]]) = pack8(pB[2 * gi], pB[2 * gi + 1]); \
  } while (0)

  f32x4 acc[4][4];
#pragma unroll
  for (int mf = 0; mf < 4; ++mf)
#pragma unroll
    for (int nf = 0; nf < 4; ++nf) acc[mf][nf] = (f32x4){0.f, 0.f, 0.f, 0.f};

#define COMP(P)                                                              \
  do {                                                                       \
    _Pragma("unroll")                                                        \
    for (int kk = 0; kk < 2; ++kk) {                                         \
      short8 bfr[4];                                                         \
      _Pragma("unroll")                                                      \
      for (int nf = 0; nf < 4; ++nf) {                                       \
        int br = wn * 64 + nf * 16 + fr;                                     \
        bfr[nf] = *reinterpret_cast<const short8*>(                          \
            &sB[P][br * 64 + (((kk * 4 + fq) ^ (br & 7)) << 3)]);            \
      }                                                                      \
      _Pragma("unroll")                                                      \
      for (int mf = 0; mf < 4; ++mf) {                                       \
        int ar = wm * 64 + mf * 16 + fr;                                     \
        short8 afr = *reinterpret_cast<const short8*>(                       \
            &sA[P][ar * 64 + (((kk * 4 + fq) ^ (ar & 7)) << 3)]);            \
        _Pragma("unroll")                                                    \
        for (int nf = 0; nf < 4; ++nf)                                       \
          acc[mf][nf] = __builtin_amdgcn_mfma_f32_16x16x32_bf16(             \
              afr, bfr[nf], acc[mf][nf], 0, 0, 0);                           \
      }                                                                      \
    }                                                                        \
  } while (0)

  const int NT = HID / 64;   // 16
  BLOADA(0);
  ASTAGE(0, 0);
  BWRITEA(0);
  BLOADB(64);
  __syncthreads();

  for (int t = 0; t < NT; t += 2) {
    if (t + 1 < NT) ASTAGE(1, (t + 1) * 64);
    if (t + 2 < NT) BLOADA((t + 2) * 64);
    COMP(0);
    if (t + 1 < NT) BWRITEB(1);
    __syncthreads();
    if (t + 2 < NT) ASTAGE(0, (t + 2) * 64);
    if (t + 3 < NT) BLOADB((t + 3) * 64);
    COMP(1);
    if (t + 2 < NT) BWRITEA(0);
    __syncthreads();
  }

#pragma unroll
  for (int mf = 0; mf < 4; ++mf) {
    int rl = wm * 64 + mf * 16 + fq * 4;
#pragma unroll
    for (int jj = 0; jj < 4; ++jj) {
      int gm = mt * 128 + rl + jj;
      if (gm < cnt) {
#pragma unroll
        for (int nf = 0; nf < 2; ++nf) {
          float h1 = acc[mf][nf][jj];
          float h3 = acc[mf][nf + 2][jj];
          float sv = h1 / (1.f + expf(-h1)) * h3;
          hbuf[(size_t)(off + gm) * FFNDIM + ntb + wn * 32 + nf * 16 + fr] = f2bf(sv);
        }
      }
    }
  }
#undef ASTAGE
#undef BLOADA
#undef BLOADB
#undef BWRITEA
#undef BWRITEB
#undef COMP
}

// ======== GEMM2: 128 tokens x 64 hid-cols; 4 waves(2x2); BK=64; split-K=2; NT=16 ========
__global__ __launch_bounds__(256) void gemm2_v7(
    const unsigned short* __restrict__ hbuf, const float* __restrict__ w2,
    const int* __restrict__ counts, const int* __restrict__ offsets,
    float* __restrict__ Yg) {
  int zz = blockIdx.z;
  int e = zz & 7, kz = zz >> 3;
  int cnt = counts[e];
  int nt = blockIdx.x, mt = blockIdx.y;
  if (cnt == 0 || mt * 128 >= cnt) return;
  int off = offsets[e];
  int ntb = nt * 64;
  int kbase = kz * (FFNDIM / 2);

  __shared__ alignas(16) unsigned short sA[2][128 * 64];
  __shared__ alignas(16) unsigned short sB[2][64 * 64];

  int tid = threadIdx.x;
  int lane = tid & 63, wid = tid >> 6;
  int wm = wid >> 1, wn = wid & 1;
  int fr = lane & 15, fq = lane >> 4;

  int g_lin = (((lane & 7) ^ (lane >> 3)) << 3);
  size_t asrc[4];
#pragma unroll
  for (int j = 0; j < 4; ++j) {
    int rg = mt * 128 + j * 32 + wid * 8 + (lane >> 3);
    if (rg > cnt - 1) rg = cnt - 1;
    asrc[j] = (size_t)(off + rg) * FFNDIM + kbase + g_lin;
  }
#define ASTAGE(P, K0)                                                        \
  do {                                                                       \
    _Pragma("unroll")                                                        \
    for (int j = 0; j < 4; ++j)                                              \
      gload_lds16(hbuf + asrc[j] + (K0), &sA[P][(j * 32 + wid * 8) * 64]);   \
  } while (0)

  // B: 64 rows x 64 K; thread: row rb=tid>>2, granules gset..gset+1
  int rb = tid >> 2;
  int gset = (tid & 3) * 2;
  const float* bsrc = w2 + ((size_t)e * HID + (ntb + rb)) * FFNDIM + kbase;
  int bws[2];
#pragma unroll
  for (int gi = 0; gi < 2; ++gi)
    bws[gi] = rb * 64 + (((gset + gi) ^ (rb & 7)) << 3);

  float4 pA[4], pB[4];
#define BLOADA(K0)                                                           \
  do {                                                                       \
    _Pragma("unroll")                                                        \
    for (int gi = 0; gi < 2; ++gi) {                                         \
      pA[2 * gi]     = *(const float4*)(bsrc + (K0) + (gset + gi) * 8);      \
      pA[2 * gi + 1] = *(const float4*)(bsrc + (K0) + (gset + gi) * 8 + 4);  \
    }                                                                        \
  } while (0)
#define BLOADB(K0)                                                           \
  do {                                                                       \
    _Pragma("unroll")                                                        \
    for (int gi = 0; gi < 2; ++gi) {                                         \
      pB[2 * gi]     = *(const float4*)(bsrc + (K0) + (gset + gi) * 8);      \
      pB[2 * gi + 1] = *(const float4*)(bsrc + (K0) + (gset + gi) * 8 + 4);  \
    }                                                                        \
  } while (0)
#define BWRITEA(P)                                                           \
  do {                                                                       \
    _Pragma("unroll")                                                        \
    for (int gi = 0; gi < 2; ++gi)                                           \
      *reinterpret_cast<short8*>(&sB[P][bws[gi]]) = pack8(pA[2 * gi], pA[2 * gi + 1]); \
  } while (0)
#define BWRITEB(P)                                                           \
  do {                                                                       \
    _Pragma("unroll")                                                        \
    for (int gi = 0; gi < 2; ++gi)                                           \
      *reinterpret_cast<short8*>(&sB[P][bws[gi]]) = pack8(pB[2 * gi], pB[2 * gi + 1]); \
  } while (0)

  f32x4 acc[4][2];
#pragma unroll
  for (int mf = 0; mf < 4; ++mf)
#pragma unroll
    for (int nf = 0; nf < 2; ++nf) acc[mf][nf] = (f32x4){0.f, 0.f, 0.f, 0.f};

#define COMP(P)                                                              \
  do {                                                                       \
    _Pragma("unroll")                                                        \
    for (int kk = 0; kk < 2; ++kk) {                                         \
      short8 bfr[2];                                                         \
      _Pragma("unroll")                                                      \
      for (int nf = 0; nf < 2; ++nf) {                                       \
        int br = wn * 32 + nf * 16 + fr;                                     \
        bfr[nf] = *reinterpret_cast<const short8*>(                          \
            &sB[P][br * 64 + (((kk * 4 + fq) ^ (br & 7)) << 3)]);            \
      }                                                                      \
      _Pragma("unroll")                                                      \
      for (int mf = 0; mf < 4; ++mf) {                                       \
        int ar = wm * 64 + mf * 16 + fr;                                     \
        short8 afr = *reinterpret_cast<const short8*>(                       \
            &sA[P][ar * 64 + (((kk * 4 + fq) ^ (ar & 7)) << 3)]);            \
        _Pragma("unroll")                                                    \
        for (int nf = 0; nf < 2; ++nf)                                       \
          acc[mf][nf] = __builtin_amdgcn_mfma_f32_16x16x32_bf16(             \
              afr, bfr[nf], acc[mf][nf], 0, 0, 0);                           \
      }                                                                      \
    }                                                                        \
  } while (0)

  const int NT = (FFNDIM / 2) / 64;   // 16
  BLOADA(0);
  ASTAGE(0, 0);
  BWRITEA(0);
  BLOADB(64);
  __syncthreads();

  for (int t = 0; t < NT; t += 2) {
    if (t + 1 < NT) ASTAGE(1, (t + 1) * 64);
    if (t + 2 < NT) BLOADA((t + 2) * 64);
    COMP(0);
    if (t + 1 < NT) BWRITEB(1);
    __syncthreads();
    if (t + 2 < NT) ASTAGE(0, (t + 2) * 64);
    if (t + 3 < NT) BLOADB((t + 3) * 64);
    COMP(1);
    if (t + 2 < NT) BWRITEA(0);
    __syncthreads();
  }

  float* yp = Yg + (size_t)kz * YPSTR;
#pragma unroll
  for (int mf = 0; mf < 4; ++mf) {
    int rl = wm * 64 + mf * 16 + fq * 4;
#pragma unroll
    for (int jj = 0; jj < 4; ++jj) {
      int gm = mt * 128 + rl + jj;
      if (gm < cnt) {
#pragma unroll
        for (int nf = 0; nf < 2; ++nf)
          yp[(size_t)(off + gm) * HID + ntb + wn * 32 + nf * 16 + fr] = acc[mf][nf][jj];
      }
    }
  }
#undef ASTAGE
#undef BLOADA
#undef BLOADB
#undef BWRITEA
#undef BWRITEB
#undef COMP
}

// ======== combine: out[t] = tw0*(Y0[r0]+Y1[r0]) + tw1*(Y0[r1]+Y1[r1]) ========
__global__ __launch_bounds__(256) void combine_kernel(
    const float* __restrict__ Yg, const int* __restrict__ tok_rows,
    const float* __restrict__ top_w, float* __restrict__ out) {
  int t = blockIdx.x;
  int c = threadIdx.x * 4;
  int r0 = tok_rows[t * 2 + 0];
  int r1 = tok_rows[t * 2 + 1];
  float tw0 = top_w[t * 2 + 0];
  float tw1 = top_w[t * 2 + 1];
  const float* Y0 = Yg;
  const float* Y1 = Yg + (size_t)YPSTR;
  float4 a0 = *reinterpret_cast<const float4*>(Y0 + (size_t)r0 * HID + c);
  float4 b0 = *reinterpret_cast<const float4*>(Y1 + (size_t)r0 * HID + c);
  float4 a1 = *reinterpret_cast<const float4*>(Y0 + (size_t)r1 * HID + c);
  float4 b1 = *reinterpret_cast<const float4*>(Y1 + (size_t)r1 * HID + c);
  float4 o;
  o.x = tw0 * (a0.x + b0.x) + tw1 * (a1.x + b1.x);
  o.y = tw0 * (a0.y + b0.y) + tw1 * (a1.y + b1.y);
  o.z = tw0 * (a0.z + b0.z) + tw1 * (a1.z + b1.z);
  o.w = tw0 * (a0.w + b0.w) + tw1 * (a1.w + b1.w);
  *reinterpret_cast<float4*>(out + (size_t)t * HID + c) = o;
}

extern "C" void kernel_launch(void* const* d_in, const int* in_sizes, int n_in,
                              void* d_out, int out_size, void* d_ws, size_t ws_size,
                              hipStream_t stream) {
  const float* x  = (const float*)d_in[0];
  const float* gw = (const float*)d_in[1];
  const float* w1 = (const float*)d_in[2];
  const float* w3 = (const float*)d_in[3];
  const float* w2 = (const float*)d_in[4];
  float* out = (float*)d_out;

  char* ws = (char*)d_ws;
  int*   counts   = (int*)(ws + 0);
  int*   cursor   = (int*)(ws + 32);
  int*   offsets  = (int*)(ws + 64);
  int*   top_i    = (int*)(ws + 1024);
  float* top_w    = (float*)(ws + 17408);
  int*   row_tok  = (int*)(ws + 33792);
  int*   tok_rows = (int*)(ws + 50176);
  unsigned short* Xg   = (unsigned short*)(ws + 66560);     // 4224*1024 bf16
  unsigned short* hbuf = (unsigned short*)(ws + 8717312);   // 4224*2048 bf16
  float*          Yg   = (float*)(ws + 26018816);           // 2 planes * 4224*1024 f32

  hipMemsetAsync(ws, 0, 128, stream);

  router_kernel<<<T_TOK / 4, 256, 0, stream>>>(x, gw, counts, top_i, top_w);
  offsets_kernel<<<1, 64, 0, stream>>>(counts, offsets);
  scatter_kernel<<<(T_TOK + 255) / 256, 256, 0, stream>>>(top_i, top_w, offsets, cursor, row_tok, tok_rows);
  gather_kernel<<<T_TOK * 2, 256, 0, stream>>>(x, row_tok, Xg);

  // gemm1: 32 n-tiles (64 ffn-cols), mt up to 16 (worst-case cnt=2048), 8 experts
  gemm1_v7<<<dim3(FFNDIM / 64, 16, NEXP), 256, 0, stream>>>(Xg, w1, w3, counts, offsets, hbuf);
  // gemm2: 16 n-tiles (64 hid-cols), mt up to 16, 8 experts x 2 split-K
  gemm2_v7<<<dim3(HID / 64, 16, NEXP * 2), 256, 0, stream>>>(hbuf, w2, counts, offsets, Yg);
  combine_kernel<<<T_TOK, 256, 0, stream>>>(Yg, tok_rows, top_w, out);
}

// Round 8
// 251.913 us; speedup vs baseline: 1.1858x; 1.1858x over previous
//
#include <hip/hip_runtime.h>
#include <hip/hip_bf16.h>

#define T_TOK 2048
#define HID 1024
#define FFNDIM 2048
#define NEXP 8

typedef __attribute__((ext_vector_type(8))) short short8;
typedef __attribute__((ext_vector_type(4))) float f32x4;

__device__ inline unsigned short f2bf(float f) {
  union { float f; unsigned int u; } v; v.f = f;
  unsigned int u = v.u;
  unsigned int r = (u + 0x7fffu + ((u >> 16) & 1u)) >> 16;
  return (unsigned short)r;
}

__device__ inline void gload_lds16(const void* g, void* l) {
  __builtin_amdgcn_global_load_lds((const __attribute__((address_space(1))) void*)g,
                                   (__attribute__((address_space(3))) void*)l, 16, 0, 0);
}

// ---------------- router ----------------
__global__ __launch_bounds__(256) void router_kernel(
    const float* __restrict__ x, const float* __restrict__ gw,
    int* __restrict__ counts, int* __restrict__ top_i, float* __restrict__ top_w) {
  int lane = threadIdx.x & 63;
  int t = blockIdx.x * 4 + (threadIdx.x >> 6);
  if (t >= T_TOK) return;
  float xv[16];
#pragma unroll
  for (int i = 0; i < 16; ++i) xv[i] = x[(size_t)t * HID + i * 64 + lane];
  float logit[NEXP];
#pragma unroll
  for (int e = 0; e < NEXP; ++e) {
    float s = 0.f;
#pragma unroll
    for (int i = 0; i < 16; ++i) s += xv[i] * gw[e * HID + i * 64 + lane];
#pragma unroll
    for (int off = 32; off > 0; off >>= 1) s += __shfl_xor(s, off);
    logit[e] = s;
  }
  if (lane == 0) {
    float mx = logit[0];
#pragma unroll
    for (int e = 1; e < NEXP; ++e) mx = fmaxf(mx, logit[e]);
    float p[NEXP]; float sum = 0.f;
#pragma unroll
    for (int e = 0; e < NEXP; ++e) { p[e] = expf(logit[e] - mx); sum += p[e]; }
#pragma unroll
    for (int e = 0; e < NEXP; ++e) p[e] /= sum;
    int i0 = 0;
#pragma unroll
    for (int e = 1; e < NEXP; ++e) if (p[e] > p[i0]) i0 = e;
    int i1 = (i0 == 0) ? 1 : 0;
#pragma unroll
    for (int e = 0; e < NEXP; ++e) if (e != i0 && p[e] > p[i1]) i1 = e;
    float w0 = p[i0], w1v = p[i1];
    float s2 = w0 + w1v;
    w0 /= s2; w1v /= s2;
    top_i[t * 2 + 0] = i0; top_i[t * 2 + 1] = i1;
    top_w[t * 2 + 0] = w0; top_w[t * 2 + 1] = w1v;
    atomicAdd(&counts[i0], 1);
    atomicAdd(&counts[i1], 1);
  }
}

__global__ void offsets_kernel(const int* __restrict__ counts, int* __restrict__ offsets) {
  if (threadIdx.x == 0 && blockIdx.x == 0) {
    int s = 0;
    for (int e = 0; e < NEXP; ++e) { offsets[e] = s; s += counts[e]; }
    offsets[NEXP] = s;
  }
}

__global__ __launch_bounds__(256) void scatter_kernel(
    const int* __restrict__ top_i, const float* __restrict__ top_w,
    const int* __restrict__ offsets, int* __restrict__ cursor,
    int* __restrict__ row_tok, int* __restrict__ tok_rows) {
  int t = blockIdx.x * 256 + threadIdx.x;
  if (t >= T_TOK) return;
#pragma unroll
  for (int k = 0; k < 2; ++k) {
    int e = top_i[t * 2 + k];
    int p = atomicAdd(&cursor[e], 1);
    int idx = offsets[e] + p;
    row_tok[idx] = t;
    tok_rows[t * 2 + k] = idx;
  }
}

__global__ __launch_bounds__(256) void gather_kernel(
    const float* __restrict__ x, const int* __restrict__ row_tok,
    unsigned short* __restrict__ Xg) {
  int r = blockIdx.x;
  int t = row_tok[r];
  int c = threadIdx.x * 4;
  float4 v = *reinterpret_cast<const float4*>(x + (size_t)t * HID + c);
  ushort4 o;
  o.x = f2bf(v.x); o.y = f2bf(v.y); o.z = f2bf(v.z); o.w = f2bf(v.w);
  *reinterpret_cast<ushort4*>(Xg + (size_t)r * HID + c) = o;
}

// ---------------- fp32 -> bf16 weight converts ----------------
__global__ __launch_bounds__(256) void w2bf2_kernel(
    const float4* __restrict__ s0, const float4* __restrict__ s1,
    ushort4* __restrict__ d0, ushort4* __restrict__ d1, int n4) {
  int i = blockIdx.x * 256 + threadIdx.x;
  if (i >= n4) return;
  const float4* s = blockIdx.y ? s1 : s0;
  ushort4* d = blockIdx.y ? d1 : d0;
  float4 v = s[i];
  ushort4 o;
  o.x = f2bf(v.x); o.y = f2bf(v.y); o.z = f2bf(v.z); o.w = f2bf(v.w);
  d[i] = o;
}

__global__ __launch_bounds__(256) void w2bf1_kernel(
    const float4* __restrict__ s, ushort4* __restrict__ d, int n4) {
  int i = blockIdx.x * 256 + threadIdx.x;
  if (i >= n4) return;
  float4 v = s[i];
  ushort4 o;
  o.x = f2bf(v.x); o.y = f2bf(v.y); o.z = f2bf(v.z); o.w = f2bf(v.w);
  d[i] = o;
}

// ================= GEMM cores (m230-V0 geometry: 256-row tile, 8 waves 2Mx4N) ========
// gemm1: 256 tokens x 128 ffn-cols (w1&w3 interleaved per-32 -> B tile 256 rows)
// B tile row r: wn_=r>>6, s=r&63; s<32 -> Wb1 col ntb+wn_*32+s ; s>=32 -> Wb3 col ntb+wn_*32+(s-32)
// wave (wm,wn): tokens wm*128+mf*16.., B rows wn*64+nf*16+fr (nf 0,1=w1; 2,3=w3 same cols)
template <int BK>
__device__ __forceinline__ void gemm1_core(
    unsigned short* __restrict__ sA, unsigned short* __restrict__ sB,  // [2][256*BK] each
    const unsigned short* __restrict__ Xg,
    const unsigned short* __restrict__ Wb1, const unsigned short* __restrict__ Wb3,
    const int* __restrict__ counts, const int* __restrict__ offsets,
    unsigned short* __restrict__ hbuf) {
  constexpr int GRAN = BK / 8;            // 16B granules per row
  constexpr int RPI = 4096 / BK;          // rows per DMA issue (512 lanes x 8 elems)
  constexpr int AISS = 256 / RPI;         // issues per 256-row tile
  constexpr int RPW = 64 / GRAN;          // rows per wave per issue
  constexpr int LOG2G = (BK == 64) ? 3 : 2;
  constexpr int NKK = BK / 32;
  constexpr int TILE = 256 * BK;

  int e = blockIdx.z;
  int cnt = counts[e];
  int nt = blockIdx.x, mt = blockIdx.y;
  if (cnt == 0 || mt * 256 >= cnt) return;
  int off = offsets[e];
  int ntb = nt * 128;

  int tid = threadIdx.x, lane = tid & 63, wid = tid >> 6;
  int wm = wid >> 2, wn = wid & 3;
  int fr = lane & 15, fq = lane >> 4;

  int ri = tid >> LOG2G;                   // row within issue
  int g = tid & (GRAN - 1);
  int gsw = (g ^ (ri & (GRAN - 1))) * 8;   // pre-swizzled source granule (elems)

  size_t asrc[AISS];
  const unsigned short* bsrc[AISS];
  int lbase[AISS];
#pragma unroll
  for (int j = 0; j < AISS; ++j) {
    int r = j * RPI + ri;
    int rg = mt * 256 + r; if (rg > cnt - 1) rg = cnt - 1;
    asrc[j] = (size_t)(off + rg) * HID + gsw;
    int wn_ = r >> 6, s = r & 63;
    const unsigned short* mat = (s < 32) ? Wb1 : Wb3;
    bsrc[j] = mat + ((size_t)e * FFNDIM + (ntb + wn_ * 32 + (s & 31))) * HID + gsw;
    lbase[j] = (j * RPI + wid * RPW) * BK;
  }

#define STAGE1(P, K0)                                                       \
  do {                                                                      \
    _Pragma("unroll")                                                       \
    for (int j = 0; j < AISS; ++j) {                                        \
      gload_lds16(Xg + asrc[j] + (K0), &sA[(P) * TILE + lbase[j]]);         \
      gload_lds16(bsrc[j] + (K0), &sB[(P) * TILE + lbase[j]]);              \
    }                                                                       \
  } while (0)

  f32x4 acc[8][4];
#pragma unroll
  for (int mf = 0; mf < 8; ++mf)
#pragma unroll
    for (int nf = 0; nf < 4; ++nf) acc[mf][nf] = (f32x4){0.f, 0.f, 0.f, 0.f};

#define COMP1(P)                                                            \
  do {                                                                      \
    _Pragma("unroll")                                                       \
    for (int kk = 0; kk < NKK; ++kk) {                                      \
      short8 bfr[4];                                                        \
      _Pragma("unroll")                                                     \
      for (int nf = 0; nf < 4; ++nf) {                                      \
        int R = wn * 64 + nf * 16 + fr;                                     \
        bfr[nf] = *reinterpret_cast<const short8*>(                         \
            &sB[(P) * TILE + R * BK + (((kk * 4 + fq) ^ (R & (GRAN - 1))) << 3)]); \
      }                                                                     \
      _Pragma("unroll")                                                     \
      for (int mf = 0; mf < 8; ++mf) {                                      \
        int R = wm * 128 + mf * 16 + fr;                                    \
        short8 afr = *reinterpret_cast<const short8*>(                      \
            &sA[(P) * TILE + R * BK + (((kk * 4 + fq) ^ (R & (GRAN - 1))) << 3)]); \
        _Pragma("unroll")                                                   \
        for (int nf = 0; nf < 4; ++nf)                                      \
          acc[mf][nf] = __builtin_amdgcn_mfma_f32_16x16x32_bf16(            \
              afr, bfr[nf], acc[mf][nf], 0, 0, 0);                          \
      }                                                                     \
    }                                                                       \
  } while (0)

  const int NT = HID / BK;
  STAGE1(0, 0);
  __syncthreads();
  int cur = 0;
  for (int t = 0; t < NT; ++t) {
    if (t + 1 < NT) STAGE1(cur ^ 1, (t + 1) * BK);
    COMP1(cur);
    __syncthreads();
    cur ^= 1;
  }

#pragma unroll
  for (int mf = 0; mf < 8; ++mf) {
    int rl = wm * 128 + mf * 16 + fq * 4;
#pragma unroll
    for (int jj = 0; jj < 4; ++jj) {
      int gm = mt * 256 + rl + jj;
      if (gm < cnt) {
#pragma unroll
        for (int nf = 0; nf < 2; ++nf) {
          float h1 = acc[mf][nf][jj];
          float h3 = acc[mf][nf + 2][jj];
          float sv = h1 / (1.f + expf(-h1)) * h3;
          hbuf[(size_t)(off + gm) * FFNDIM + ntb + wn * 32 + nf * 16 + fr] = f2bf(sv);
        }
      }
    }
  }
#undef STAGE1
#undef COMP1
}

// gemm2: 256 rows x 128 hid-cols; B tile 128 rows; split-K=2 -> Yg planes
template <int BK>
__device__ __forceinline__ void gemm2_core(
    unsigned short* __restrict__ sA, unsigned short* __restrict__ sB,  // [2][256*BK], [2][128*BK]
    const unsigned short* __restrict__ hbuf, const unsigned short* __restrict__ Wb2,
    const int* __restrict__ counts, const int* __restrict__ offsets,
    float* __restrict__ Yg) {
  constexpr int GRAN = BK / 8;
  constexpr int RPI = 4096 / BK;
  constexpr int AISS = 256 / RPI;
  constexpr int BISS = (128 / RPI > 0) ? 128 / RPI : 1;
  constexpr int RPW = 64 / GRAN;
  constexpr int LOG2G = (BK == 64) ? 3 : 2;
  constexpr int NKK = BK / 32;
  constexpr int ATILE = 256 * BK;
  constexpr int BTILE = 128 * BK;

  int zz = blockIdx.z;
  int e = zz & 7, kz = zz >> 3;
  int cnt = counts[e];
  int nt = blockIdx.x, mt = blockIdx.y;
  if (cnt == 0 || mt * 256 >= cnt) return;
  int off = offsets[e];
  int ntb = nt * 128;
  int kbase = kz * (FFNDIM / 2);

  int tid = threadIdx.x, lane = tid & 63, wid = tid >> 6;
  int wm = wid >> 2, wn = wid & 3;
  int fr = lane & 15, fq = lane >> 4;

  int ri = tid >> LOG2G;
  int g = tid & (GRAN - 1);
  int gsw = (g ^ (ri & (GRAN - 1))) * 8;

  size_t asrc[AISS];
  int albase[AISS];
#pragma unroll
  for (int j = 0; j < AISS; ++j) {
    int r = j * RPI + ri;
    int rg = mt * 256 + r; if (rg > cnt - 1) rg = cnt - 1;
    asrc[j] = (size_t)(off + rg) * FFNDIM + kbase + gsw;
    albase[j] = (j * RPI + wid * RPW) * BK;
  }
  const unsigned short* bsrc[BISS];
  int blbase[BISS];
#pragma unroll
  for (int j = 0; j < BISS; ++j) {
    int r = j * RPI + ri;   // 0..127
    bsrc[j] = Wb2 + ((size_t)e * HID + (ntb + r)) * FFNDIM + kbase + gsw;
    blbase[j] = (j * RPI + wid * RPW) * BK;
  }

#define STAGE2(P, K0)                                                       \
  do {                                                                      \
    _Pragma("unroll")                                                       \
    for (int j = 0; j < AISS; ++j)                                          \
      gload_lds16(hbuf + asrc[j] + (K0), &sA[(P) * ATILE + albase[j]]);     \
    _Pragma("unroll")                                                       \
    for (int j = 0; j < BISS; ++j)                                          \
      gload_lds16(bsrc[j] + (K0), &sB[(P) * BTILE + blbase[j]]);            \
  } while (0)

  f32x4 acc[8][2];
#pragma unroll
  for (int mf = 0; mf < 8; ++mf)
#pragma unroll
    for (int nf = 0; nf < 2; ++nf) acc[mf][nf] = (f32x4){0.f, 0.f, 0.f, 0.f};

#define COMP2(P)                                                            \
  do {                                                                      \
    _Pragma("unroll")                                                       \
    for (int kk = 0; kk < NKK; ++kk) {                                      \
      short8 bfr[2];                                                        \
      _Pragma("unroll")                                                     \
      for (int nf = 0; nf < 2; ++nf) {                                      \
        int R = wn * 32 + nf * 16 + fr;                                     \
        bfr[nf] = *reinterpret_cast<const short8*>(                         \
            &sB[(P) * BTILE + R * BK + (((kk * 4 + fq) ^ (R & (GRAN - 1))) << 3)]); \
      }                                                                     \
      _Pragma("unroll")                                                     \
      for (int mf = 0; mf < 8; ++mf) {                                      \
        int R = wm * 128 + mf * 16 + fr;                                    \
        short8 afr = *reinterpret_cast<const short8*>(                      \
            &sA[(P) * ATILE + R * BK + (((kk * 4 + fq) ^ (R & (GRAN - 1))) << 3)]); \
        _Pragma("unroll")                                                   \
        for (int nf = 0; nf < 2; ++nf)                                      \
          acc[mf][nf] = __builtin_amdgcn_mfma_f32_16x16x32_bf16(            \
              afr, bfr[nf], acc[mf][nf], 0, 0, 0);                          \
      }                                                                     \
    }                                                                       \
  } while (0)

  const int NT = (FFNDIM / 2) / BK;
  STAGE2(0, 0);
  __syncthreads();
  int cur = 0;
  for (int t = 0; t < NT; ++t) {
    if (t + 1 < NT) STAGE2(cur ^ 1, (t + 1) * BK);
    COMP2(cur);
    __syncthreads();
    cur ^= 1;
  }

  float* yp = Yg + (size_t)kz * (4096 * HID);
#pragma unroll
  for (int mf = 0; mf < 8; ++mf) {
    int rl = wm * 128 + mf * 16 + fq * 4;
#pragma unroll
    for (int jj = 0; jj < 4; ++jj) {
      int gm = mt * 256 + rl + jj;
      if (gm < cnt) {
#pragma unroll
        for (int nf = 0; nf < 2; ++nf)
          yp[(size_t)(off + gm) * HID + ntb + wn * 32 + nf * 16 + fr] = acc[mf][nf][jj];
      }
    }
  }
#undef STAGE2
#undef COMP2
}

// -------- wrappers: dynamic-LDS BK=64 (preferred) and static BK=32 (fallback) --------
__global__ __launch_bounds__(512, 2) void gemm1_dyn(
    const unsigned short* Xg, const unsigned short* Wb1, const unsigned short* Wb3,
    const int* counts, const int* offsets, unsigned short* hbuf) {
  extern __shared__ unsigned short smem1[];
  gemm1_core<64>(smem1, smem1 + 2 * 256 * 64, Xg, Wb1, Wb3, counts, offsets, hbuf);
}

__global__ __launch_bounds__(512, 2) void gemm1_sta(
    const unsigned short* Xg, const unsigned short* Wb1, const unsigned short* Wb3,
    const int* counts, const int* offsets, unsigned short* hbuf) {
  __shared__ alignas(16) unsigned short sA[2 * 256 * 32];
  __shared__ alignas(16) unsigned short sB[2 * 256 * 32];
  gemm1_core<32>(sA, sB, Xg, Wb1, Wb3, counts, offsets, hbuf);
}

__global__ __launch_bounds__(512, 2) void gemm2_dyn(
    const unsigned short* hbuf, const unsigned short* Wb2,
    const int* counts, const int* offsets, float* Yg) {
  extern __shared__ unsigned short smem2[];
  gemm2_core<64>(smem2, smem2 + 2 * 256 * 64, hbuf, Wb2, counts, offsets, Yg);
}

__global__ __launch_bounds__(512, 2) void gemm2_sta(
    const unsigned short* hbuf, const unsigned short* Wb2,
    const int* counts, const int* offsets, float* Yg) {
  __shared__ alignas(16) unsigned short sA[2 * 256 * 32];
  __shared__ alignas(16) unsigned short sB[2 * 128 * 32];
  gemm2_core<32>(sA, sB, hbuf, Wb2, counts, offsets, Yg);
}

// ======== combine: out[t] = tw0*(Y0[r0]+Y1[r0]) + tw1*(Y0[r1]+Y1[r1]) ========
__global__ __launch_bounds__(256) void combine_kernel(
    const float* __restrict__ Yg, const int* __restrict__ tok_rows,
    const float* __restrict__ top_w, float* __restrict__ out) {
  int t = blockIdx.x;
  int c = threadIdx.x * 4;
  int r0 = tok_rows[t * 2 + 0];
  int r1 = tok_rows[t * 2 + 1];
  float tw0 = top_w[t * 2 + 0];
  float tw1 = top_w[t * 2 + 1];
  const float* Y0 = Yg;
  const float* Y1 = Yg + (size_t)4096 * HID;
  float4 a0 = *reinterpret_cast<const float4*>(Y0 + (size_t)r0 * HID + c);
  float4 b0 = *reinterpret_cast<const float4*>(Y1 + (size_t)r0 * HID + c);
  float4 a1 = *reinterpret_cast<const float4*>(Y0 + (size_t)r1 * HID + c);
  float4 b1 = *reinterpret_cast<const float4*>(Y1 + (size_t)r1 * HID + c);
  float4 o;
  o.x = tw0 * (a0.x + b0.x) + tw1 * (a1.x + b1.x);
  o.y = tw0 * (a0.y + b0.y) + tw1 * (a1.y + b1.y);
  o.z = tw0 * (a0.z + b0.z) + tw1 * (a1.z + b1.z);
  o.w = tw0 * (a0.w + b0.w) + tw1 * (a1.w + b1.w);
  *reinterpret_cast<float4*>(out + (size_t)t * HID + c) = o;
}

extern "C" void kernel_launch(void* const* d_in, const int* in_sizes, int n_in,
                              void* d_out, int out_size, void* d_ws, size_t ws_size,
                              hipStream_t stream) {
  const float* x  = (const float*)d_in[0];
  const float* gw = (const float*)d_in[1];
  const float* w1 = (const float*)d_in[2];
  const float* w3 = (const float*)d_in[3];
  const float* w2 = (const float*)d_in[4];
  float* out = (float*)d_out;

  char* ws = (char*)d_ws;
  int*   counts   = (int*)(ws + 0);
  int*   cursor   = (int*)(ws + 32);
  int*   offsets  = (int*)(ws + 64);
  int*   top_i    = (int*)(ws + 1024);
  float* top_w    = (float*)(ws + 17408);
  int*   row_tok  = (int*)(ws + 33792);
  int*   tok_rows = (int*)(ws + 50176);
  unsigned short* Xg   = (unsigned short*)(ws + 66560);     // 4224*1024 bf16
  unsigned short* hbuf = (unsigned short*)(ws + 8717312);   // 4224*2048 bf16
  unsigned short* Wb1  = (unsigned short*)(ws + 26018816);  // 32 MB (reused for Wb2 later)
  unsigned short* Wb3  = (unsigned short*)(ws + 59573248);  // 32 MB
  float*          Yg   = (float*)(ws + 93127680);           // 2 planes * 4096*1024 f32
  unsigned short* Wb2  = Wb1;                               // reuse after gemm1 done

  // opt into >64KB dynamic LDS; deterministic every call
  hipError_t a1 = hipFuncSetAttribute((const void*)gemm1_dyn,
                      hipFuncAttributeMaxDynamicSharedMemorySize, 131072);
  hipError_t a2 = hipFuncSetAttribute((const void*)gemm2_dyn,
                      hipFuncAttributeMaxDynamicSharedMemorySize, 98304);
  bool dyn = (a1 == hipSuccess) && (a2 == hipSuccess);

  hipMemsetAsync(ws, 0, 128, stream);

  router_kernel<<<T_TOK / 4, 256, 0, stream>>>(x, gw, counts, top_i, top_w);
  offsets_kernel<<<1, 64, 0, stream>>>(counts, offsets);
  scatter_kernel<<<(T_TOK + 255) / 256, 256, 0, stream>>>(top_i, top_w, offsets, cursor, row_tok, tok_rows);
  gather_kernel<<<T_TOK * 2, 256, 0, stream>>>(x, row_tok, Xg);

  const int n4 = NEXP * FFNDIM * HID / 4;   // 4,194,304 float4 per tensor
  w2bf2_kernel<<<dim3(n4 / 256, 2), 256, 0, stream>>>(
      (const float4*)w1, (const float4*)w3, (ushort4*)Wb1, (ushort4*)Wb3, n4);

  if (dyn) {
    gemm1_dyn<<<dim3(16, 8, NEXP), 512, 131072, stream>>>(Xg, Wb1, Wb3, counts, offsets, hbuf);
  } else {
    gemm1_sta<<<dim3(16, 8, NEXP), 512, 0, stream>>>(Xg, Wb1, Wb3, counts, offsets, hbuf);
  }

  // convert w2 into Wb1's space (gemm1 has consumed Wb1 by now; stream-ordered)
  w2bf1_kernel<<<n4 / 256, 256, 0, stream>>>((const float4*)w2, (ushort4*)Wb2, n4);

  if (dyn) {
    gemm2_dyn<<<dim3(8, 8, NEXP * 2), 512, 98304, stream>>>(hbuf, Wb2, counts, offsets, Yg);
  } else {
    gemm2_sta<<<dim3(8, 8, NEXP * 2), 512, 0, stream>>>(hbuf, Wb2, counts, offsets, Yg);
  }

  combine_kernel<<<T_TOK, 256, 0, stream>>>(Yg, tok_rows, top_w, out);
}